// Round 15
// baseline (425.189 us; speedup 1.0000x reference)
//
#include <hip/hip_runtime.h>

#define D 256
#define GSIZE 16          // nodes per agg_gemm block
#define TN 16
#define CSHIFT 8
#define CBIN 256          // nodes per coarse bin
#define NCMAX 512         // max coarse bins (pass-A LDS hist 2 KB)
#define CAPC 9216         // csr region per coarse bin (mean 8192)
#define NB_P 256          // pass-A scatter blocks
#define TILESHIFT 12      // src tile = src>>12 (2.1 MB of fbf per tile)
#define NKEY 8192         // 256 dstLocal x 32 tiles

using bf16x8 = __attribute__((ext_vector_type(8))) short;
using f32x4  = __attribute__((ext_vector_type(4))) float;

__device__ inline float bf_lo(unsigned int u) {
    return __builtin_bit_cast(float, u << 16);
}
__device__ inline float bf_hi(unsigned int u) {
    return __builtin_bit_cast(float, u & 0xffff0000u);
}
__device__ inline unsigned short f2bf(float f) {
    unsigned int x = __builtin_bit_cast(unsigned int, f);
    unsigned int r = (x + 0x7fffu + ((x >> 16) & 1u)) >> 16;   // RNE
    return (unsigned short)r;
}

// ---------------------------------------------------------------------------
// Pass A: coarse scatter (dst>>8) || conv_feature || conv_w.
// Coarse bins keep the active write-line set << 4 MB/XCD L2 so partial 4B
// writes coalesce. csrA entry: (src<<8) | (dst&255).
// ---------------------------------------------------------------------------
__global__ __launch_bounds__(256) void part_kernel(
    const int* __restrict__ src, const int* __restrict__ dst,
    int* __restrict__ gcntC, int* __restrict__ csrA,
    const float* __restrict__ feature, unsigned short* __restrict__ fbf, long n8,
    const float* __restrict__ W, unsigned short* __restrict__ Wt,
    int E, int NC, int chunk, int nConvF)
{
    __shared__ int h[NCMAX];
    const int b = blockIdx.x, t = threadIdx.x;

    if (b < NB_P) {
        for (int i = t; i < NC; i += 256) h[i] = 0;
        __syncthreads();
        const int beg = b * chunk;
        const int end = min(beg + chunk, E);
        for (int i = beg + t; i < end; i += 256)
            atomicAdd(&h[dst[i] >> CSHIFT], 1);
        __syncthreads();
        for (int i = t; i < NC; i += 256) {
            int c = h[i];
            h[i] = c ? atomicAdd(&gcntC[i], c) : 0;
        }
        __syncthreads();
        for (int i = beg + t; i < end; i += 256) {
            int d = dst[i];
            int c = d >> CSHIFT;
            int r = atomicAdd(&h[c], 1);
            if (r < CAPC)
                csrA[(size_t)c * CAPC + r] = (src[i] << CSHIFT) | (d & (CBIN - 1));
        }
        return;
    }
    if (b < NB_P + nConvF) {
        long i = (long)(b - NB_P) * 256 + t;
        if (i < n8) {
            const float4* p = reinterpret_cast<const float4*>(feature + i * 8);
            float4 v0 = p[0], v1 = p[1];
            uint4 r;
            r.x = (unsigned int)f2bf(v0.x) | ((unsigned int)f2bf(v0.y) << 16);
            r.y = (unsigned int)f2bf(v0.z) | ((unsigned int)f2bf(v0.w) << 16);
            r.z = (unsigned int)f2bf(v1.x) | ((unsigned int)f2bf(v1.y) << 16);
            r.w = (unsigned int)f2bf(v1.z) | ((unsigned int)f2bf(v1.w) << 16);
            *reinterpret_cast<uint4*>(fbf + i * 8) = r;
        }
        return;
    }
    int i = (b - NB_P - nConvF) * 256 + t;
    if (i < D * D / 4) {
        int n  = i >> 6;
        int k0 = (i & 63) * 4;
        float a  = W[(size_t)(k0 + 0) * D + n];
        float bb = W[(size_t)(k0 + 1) * D + n];
        float c  = W[(size_t)(k0 + 2) * D + n];
        float d  = W[(size_t)(k0 + 3) * D + n];
        uint2 r;
        r.x = (unsigned int)f2bf(a) | ((unsigned int)f2bf(bb) << 16);
        r.y = (unsigned int)f2bf(c) | ((unsigned int)f2bf(d) << 16);
        *reinterpret_cast<uint2*>(Wt + (size_t)n * D + k0) = r;
    }
}

// ---------------------------------------------------------------------------
// Pass B: full (node, src-tile) counting sort per coarse bin.
// key = (dstLocal<<5) | (src>>TILESHIFT): orders edges by node, then by
// 2.1 MB src tile (L2-locality sweep for the gather). Thread t owns node
// t's 32 keys, so node offsets/counts fall out of the hierarchical prefix.
// Outputs: csrB (plain src, bin-contiguous), nodeBeg/nodeCnt (absolute).
// ---------------------------------------------------------------------------
__global__ __launch_bounds__(256) void regroup_kernel(
    const int* __restrict__ csrA, const int* __restrict__ gcntC,
    int* __restrict__ csrB, int* __restrict__ nodeBeg, int* __restrict__ nodeCnt,
    int N)
{
    __shared__ int h[NKEY];                    // 32 KB: hist -> prefix -> cursors
    __shared__ int sorted[CAPC];               // 36.9 KB
    __shared__ int psum[256];
    __shared__ int nBegL[CBIN], nCntL[CBIN];
    const int c = blockIdx.x, t = threadIdx.x;
    const size_t rbeg = (size_t)c * CAPC;
    const int cnt = min(gcntC[c], CAPC);

    for (int i = t; i < NKEY; i += 256) h[i] = 0;
    __syncthreads();
    for (int i = t; i < cnt; i += 256) {
        int p = csrA[rbeg + i];
        int key = ((p & (CBIN - 1)) << 5) | ((p >> CSHIFT) >> TILESHIFT);
        atomicAdd(&h[key], 1);
    }
    __syncthreads();
    // hierarchical exclusive prefix; thread t covers node t's 32 keys
    int local = 0;
#pragma unroll
    for (int j = 0; j < 32; ++j) local += h[(t << 5) + j];
    psum[t] = local;
    nCntL[t] = local;
    __syncthreads();
    for (int off = 1; off < 256; off <<= 1) {
        int v = (t >= off) ? psum[t - off] : 0;
        __syncthreads();
        if (t >= off) psum[t] += v;
        __syncthreads();
    }
    int run = (t == 0) ? 0 : psum[t - 1];
    nBegL[t] = run;
#pragma unroll
    for (int j = 0; j < 32; ++j) {
        int idx = (t << 5) + j;
        int cc = h[idx];
        h[idx] = run;
        run += cc;
    }
    __syncthreads();
    // scatter into sorted[] (h = cursors), store plain src
    for (int i = t; i < cnt; i += 256) {
        int p = csrA[rbeg + i];
        int key = ((p & (CBIN - 1)) << 5) | ((p >> CSHIFT) >> TILESHIFT);
        int r = atomicAdd(&h[key], 1);
        sorted[r] = p >> CSHIFT;
    }
    __syncthreads();
    for (int i = t; i < cnt; i += 256)
        csrB[rbeg + i] = sorted[i];
    {
        int node = (c << CSHIFT) + t;
        if (node < N) {
            nodeBeg[node] = (int)(rbeg + nBegL[t]);
            nodeCnt[node] = nCntL[t];
        }
    }
}

// ---------------------------------------------------------------------------
// Fused aggregate + GEMM at 16-node granularity (no in-kernel sort).
// P1: gather: 4 waves x 4 nodes; half-wave edge split, uint4 loads
//     (8 bf16 cols/lane), fp32 acc, shfl_xor merge, bf16 row -> LDS A.
//     Edge src indices come straight from node-sorted csrB (L2-hot).
// P2: GEMM 16x256 @ 256x256 MFMA + bias + ReLU -> out (fp32).
// LDS ~8.6 KB.
// ---------------------------------------------------------------------------
__global__ __launch_bounds__(256) void agg_gemm_kernel(
    const unsigned short* __restrict__ fbf,
    const int* __restrict__ csrB,
    const int* __restrict__ nodeBeg,
    const int* __restrict__ nodeCnt,
    const unsigned short* __restrict__ Wt,
    const float* __restrict__ bias,
    float* __restrict__ out, int N)
{
    __shared__ int nBeg[TN], nCnt[TN];
    __shared__ unsigned short A[TN][D + 8];    // 8448 B

    const int blk  = blockIdx.x;
    const int t    = threadIdx.x;
    const int wave = t >> 6;
    const int lane = t & 63;
    const int sub  = lane & 31;
    const int half = lane >> 5;
    const int node0 = blk * TN;
    const size_t colOff = (size_t)(sub << 3);

    if (t < TN) {
        int node = node0 + t;
        nBeg[t] = (node < N) ? nodeBeg[node] : 0;
        nCnt[t] = (node < N) ? nodeCnt[node] : 0;
    }
    __syncthreads();

    // ---- P1: gather 4 nodes per wave ----
    for (int ni = 0; ni < 4; ++ni) {
        const int l = (wave << 2) + ni;
        const int node = node0 + l;
        float a0 = 0.f, a1 = 0.f, a2 = 0.f, a3 = 0.f;
        float a4 = 0.f, a5 = 0.f, a6 = 0.f, a7 = 0.f;
        if (node < N) {
            const int b0 = nBeg[l];
            const int c0 = nCnt[l];
            int j = 0;
            for (; j + 3 < c0; j += 4) {
                int s0 = csrB[b0 + j + half];
                int s1 = csrB[b0 + j + 2 + half];
                uint4 v0 = *reinterpret_cast<const uint4*>(fbf + ((size_t)s0 << 8) + colOff);
                uint4 v1 = *reinterpret_cast<const uint4*>(fbf + ((size_t)s1 << 8) + colOff);
                a0 += bf_lo(v0.x); a1 += bf_hi(v0.x); a2 += bf_lo(v0.y); a3 += bf_hi(v0.y);
                a4 += bf_lo(v0.z); a5 += bf_hi(v0.z); a6 += bf_lo(v0.w); a7 += bf_hi(v0.w);
                a0 += bf_lo(v1.x); a1 += bf_hi(v1.x); a2 += bf_lo(v1.y); a3 += bf_hi(v1.y);
                a4 += bf_lo(v1.z); a5 += bf_hi(v1.z); a6 += bf_lo(v1.w); a7 += bf_hi(v1.w);
            }
            if (j + 1 < c0) {
                int s0 = csrB[b0 + j + half];
                uint4 v0 = *reinterpret_cast<const uint4*>(fbf + ((size_t)s0 << 8) + colOff);
                a0 += bf_lo(v0.x); a1 += bf_hi(v0.x); a2 += bf_lo(v0.y); a3 += bf_hi(v0.y);
                a4 += bf_lo(v0.z); a5 += bf_hi(v0.z); a6 += bf_lo(v0.w); a7 += bf_hi(v0.w);
                j += 2;
            }
            if (j < c0 && half == 0) {
                int s0 = csrB[b0 + j];
                uint4 v0 = *reinterpret_cast<const uint4*>(fbf + ((size_t)s0 << 8) + colOff);
                a0 += bf_lo(v0.x); a1 += bf_hi(v0.x); a2 += bf_lo(v0.y); a3 += bf_hi(v0.y);
                a4 += bf_lo(v0.z); a5 += bf_hi(v0.z); a6 += bf_lo(v0.w); a7 += bf_hi(v0.w);
            }
        }
        a0 += __shfl_xor(a0, 32); a1 += __shfl_xor(a1, 32);
        a2 += __shfl_xor(a2, 32); a3 += __shfl_xor(a3, 32);
        a4 += __shfl_xor(a4, 32); a5 += __shfl_xor(a5, 32);
        a6 += __shfl_xor(a6, 32); a7 += __shfl_xor(a7, 32);
        if (half == 0) {
            uint4 r;
            r.x = (unsigned int)f2bf(a0) | ((unsigned int)f2bf(a1) << 16);
            r.y = (unsigned int)f2bf(a2) | ((unsigned int)f2bf(a3) << 16);
            r.z = (unsigned int)f2bf(a4) | ((unsigned int)f2bf(a5) << 16);
            r.w = (unsigned int)f2bf(a6) | ((unsigned int)f2bf(a7) << 16);
            *reinterpret_cast<uint4*>(&A[l][sub << 3]) = r;
        }
    }
    __syncthreads();

    // ---- P2: GEMM 16x256 ----
    const int lr = lane & 15;
    const int lg = lane >> 4;

    bf16x8 afr[8];
#pragma unroll
    for (int ks = 0; ks < 8; ++ks)
        afr[ks] = *reinterpret_cast<const bf16x8*>(&A[lr][ks * 32 + lg * 8]);

#pragma unroll
    for (int c = 0; c < 4; ++c) {
        const int ct = (wave << 2) + c;
        f32x4 acc = {0.f, 0.f, 0.f, 0.f};
        const unsigned short* bp = Wt + (size_t)(ct * 16 + lr) * D + lg * 8;
#pragma unroll
        for (int ks = 0; ks < 8; ++ks) {
            bf16x8 bfr = *reinterpret_cast<const bf16x8*>(bp + ks * 32);
            acc = __builtin_amdgcn_mfma_f32_16x16x32_bf16(afr[ks], bfr, acc, 0, 0, 0);
        }
        const float bv = bias[ct * 16 + lr];
#pragma unroll
        for (int jj = 0; jj < 4; ++jj) {
            int row = node0 + lg * 4 + jj;
            if (row < N) {
                float v = acc[jj] + bv;
                out[(size_t)row * D + ct * 16 + lr] = v > 0.f ? v : 0.f;
            }
        }
    }
}

// ---------------------------------------------------------------------------
// Fallback kernels (ws too small): direct atomic scatter + VALU linear.
// ---------------------------------------------------------------------------
__global__ __launch_bounds__(256) void scatter_kernel(
    const float* __restrict__ feature, const int* __restrict__ src,
    const int* __restrict__ dst, float* __restrict__ agg, int E)
{
    int edge = blockIdx.x * (blockDim.x >> 6) + (threadIdx.x >> 6);
    int lane = threadIdx.x & 63;
    if (edge >= E) return;
    int s = src[edge];
    int d = dst[edge];
    const float4 v = *reinterpret_cast<const float4*>(feature + (size_t)s * D + lane * 4);
    float* o = agg + (size_t)d * D + lane * 4;
    atomicAdd(o + 0, v.x);
    atomicAdd(o + 1, v.y);
    atomicAdd(o + 2, v.z);
    atomicAdd(o + 3, v.w);
}

#define BM 32
__global__ __launch_bounds__(256) void linear_relu_kernel(
    float* __restrict__ h, const float* __restrict__ W,
    const float* __restrict__ b, int n_nodes)
{
    __shared__ float sA[BM][D];
    const int node0 = blockIdx.x * BM;
    const int t = threadIdx.x;
    for (int m = 0; m < BM; ++m) {
        int nd = node0 + m;
        sA[m][t] = (nd < n_nodes) ? h[(size_t)nd * D + t] : 0.0f;
    }
    __syncthreads();
    float acc[BM];
#pragma unroll
    for (int m = 0; m < BM; ++m) acc[m] = 0.0f;
    for (int kk = 0; kk < D; ++kk) {
        float w = W[kk * D + t];
#pragma unroll
        for (int m = 0; m < BM; ++m) acc[m] += sA[m][kk] * w;
    }
    const float bias = b[t];
    for (int m = 0; m < BM; ++m) {
        int nd = node0 + m;
        if (nd < n_nodes) {
            float v = acc[m] + bias;
            h[(size_t)nd * D + t] = v > 0.0f ? v : 0.0f;
        }
    }
}

// ---------------------------------------------------------------------------
extern "C" void kernel_launch(void* const* d_in, const int* in_sizes, int n_in,
                              void* d_out, int out_size, void* d_ws, size_t ws_size,
                              hipStream_t stream)
{
    const float* feature = (const float*)d_in[0];
    const int*   src     = (const int*)d_in[1];
    const int*   dst     = (const int*)d_in[2];
    const float* W       = (const float*)d_in[3];
    const float* b       = (const float*)d_in[4];
    float*       out     = (float*)d_out;

    const int E = in_sizes[1];
    const int N = in_sizes[0] / D;
    const int NC = (N + CBIN - 1) >> CSHIFT;    // coarse bins
    const int chunk = (E + NB_P - 1) / NB_P;

    // ---- workspace layout -------------------------------------------------
    size_t off = 0;
    auto alloc = [&](size_t bytes, size_t align) {
        off = (off + align - 1) / align * align;
        size_t r = off; off += bytes; return r;
    };
    size_t o_gcntC = alloc((size_t)NC * 4, 16);
    size_t o_csrA  = alloc((size_t)NC * CAPC * 4, 16);
    size_t o_csrB  = alloc((size_t)NC * CAPC * 4, 16);
    size_t o_nbeg  = alloc((size_t)N * 4, 16);
    size_t o_ncnt  = alloc((size_t)N * 4, 16);
    size_t o_wt    = alloc((size_t)D * D * 2, 16);
    size_t o_fbf   = alloc((size_t)N * D * 2, 16);
    size_t need_full = off;

    char* ws = (char*)d_ws;

    // guards: bin capacity (mean + 8 sigma + 16), bin count, tile range
    const double mc = (double)E / NC;
    const bool cap_ok =
        (mc + 8.0 * __builtin_sqrt(mc) + 16.0 <= (double)CAPC) &&
        (NC <= NCMAX) &&
        (N <= (32 << TILESHIFT));               // src tile id < 32

    if (ws_size >= need_full && cap_ok) {
        int* gcntC   = (int*)(ws + o_gcntC);
        int* csrA    = (int*)(ws + o_csrA);
        int* csrB    = (int*)(ws + o_csrB);
        int* nodeBeg = (int*)(ws + o_nbeg);
        int* nodeCnt = (int*)(ws + o_ncnt);
        unsigned short* Wt  = (unsigned short*)(ws + o_wt);
        unsigned short* fbf = (unsigned short*)(ws + o_fbf);

        const long n8 = (long)N * D / 8;
        const int nConvF = (int)((n8 + 255) / 256);
        const int nConvW = (D * D / 4 + 255) / 256;

        hipMemsetAsync(gcntC, 0, (size_t)NC * 4, stream);

        part_kernel<<<NB_P + nConvF + nConvW, 256, 0, stream>>>(
            src, dst, gcntC, csrA, feature, fbf, n8, W, Wt,
            E, NC, chunk, nConvF);

        regroup_kernel<<<NC, 256, 0, stream>>>(
            csrA, gcntC, csrB, nodeBeg, nodeCnt, N);

        agg_gemm_kernel<<<(N + TN - 1) / TN, 256, 0, stream>>>(
            fbf, csrB, nodeBeg, nodeCnt, Wt, b, out, N);
    } else {
        hipMemsetAsync(d_out, 0, (size_t)out_size * sizeof(float), stream);
        scatter_kernel<<<(E + 3) / 4, 256, 0, stream>>>(feature, src, dst, out, E);
        linear_relu_kernel<<<(N + BM - 1) / BM, 256, 0, stream>>>(out, W, b, N);
    }
}

// Round 16
// 404.626 us; speedup vs baseline: 1.0508x; 1.0508x over previous
//
#include <hip/hip_runtime.h>

#define D 256
#define TN 16             // nodes per agg_gemm block
#define CSHIFT 8
#define CBIN 256          // nodes per coarse bin
#define NCMAX 512         // max coarse bins (pass-A LDS hist 2 KB)
#define CAPC 9216         // csr region per coarse bin (mean 8192)
#define NB_P 256          // pass-A scatter blocks
#define CAPL 1536         // LDS edge-list capacity per 16-node group (mean 512)

using bf16x8 = __attribute__((ext_vector_type(8))) short;
using f32x4  = __attribute__((ext_vector_type(4))) float;

__device__ inline float bf_lo(unsigned int u) {
    return __builtin_bit_cast(float, u << 16);
}
__device__ inline float bf_hi(unsigned int u) {
    return __builtin_bit_cast(float, u & 0xffff0000u);
}
__device__ inline unsigned short f2bf(float f) {
    unsigned int x = __builtin_bit_cast(unsigned int, f);
    unsigned int r = (x + 0x7fffu + ((x >> 16) & 1u)) >> 16;   // RNE
    return (unsigned short)r;
}

// ---------------------------------------------------------------------------
// Pass A: coarse scatter (dst>>8) || conv_feature || conv_w.
// Coarse bins keep the active write-line set << 4 MB/XCD L2 so partial 4B
// writes coalesce. csrA entry: (src<<8) | (dst&255).
// ---------------------------------------------------------------------------
__global__ __launch_bounds__(256) void part_kernel(
    const int* __restrict__ src, const int* __restrict__ dst,
    int* __restrict__ gcntC, int* __restrict__ csrA,
    const float* __restrict__ feature, unsigned short* __restrict__ fbf, long n8,
    const float* __restrict__ W, unsigned short* __restrict__ Wt,
    int E, int NC, int chunk, int nConvF)
{
    __shared__ int h[NCMAX];
    const int b = blockIdx.x, t = threadIdx.x;

    if (b < NB_P) {
        for (int i = t; i < NC; i += 256) h[i] = 0;
        __syncthreads();
        const int beg = b * chunk;
        const int end = min(beg + chunk, E);
        for (int i = beg + t; i < end; i += 256)
            atomicAdd(&h[dst[i] >> CSHIFT], 1);
        __syncthreads();
        for (int i = t; i < NC; i += 256) {
            int c = h[i];
            h[i] = c ? atomicAdd(&gcntC[i], c) : 0;
        }
        __syncthreads();
        for (int i = beg + t; i < end; i += 256) {
            int d = dst[i];
            int c = d >> CSHIFT;
            int r = atomicAdd(&h[c], 1);
            if (r < CAPC)
                csrA[(size_t)c * CAPC + r] = (src[i] << CSHIFT) | (d & (CBIN - 1));
        }
        return;
    }
    if (b < NB_P + nConvF) {
        long i = (long)(b - NB_P) * 256 + t;
        if (i < n8) {
            const float4* p = reinterpret_cast<const float4*>(feature + i * 8);
            float4 v0 = p[0], v1 = p[1];
            uint4 r;
            r.x = (unsigned int)f2bf(v0.x) | ((unsigned int)f2bf(v0.y) << 16);
            r.y = (unsigned int)f2bf(v0.z) | ((unsigned int)f2bf(v0.w) << 16);
            r.z = (unsigned int)f2bf(v1.x) | ((unsigned int)f2bf(v1.y) << 16);
            r.w = (unsigned int)f2bf(v1.z) | ((unsigned int)f2bf(v1.w) << 16);
            *reinterpret_cast<uint4*>(fbf + i * 8) = r;
        }
        return;
    }
    int i = (b - NB_P - nConvF) * 256 + t;
    if (i < D * D / 4) {
        int n  = i >> 6;
        int k0 = (i & 63) * 4;
        float a  = W[(size_t)(k0 + 0) * D + n];
        float bb = W[(size_t)(k0 + 1) * D + n];
        float c  = W[(size_t)(k0 + 2) * D + n];
        float d  = W[(size_t)(k0 + 3) * D + n];
        uint2 r;
        r.x = (unsigned int)f2bf(a) | ((unsigned int)f2bf(bb) << 16);
        r.y = (unsigned int)f2bf(c) | ((unsigned int)f2bf(d) << 16);
        *reinterpret_cast<uint2*>(Wt + (size_t)n * D + k0) = r;
    }
}

// ---------------------------------------------------------------------------
// Pass B: per-bin full node sort (256-key LDS counting sort).
// Thread t owns local node t. Outputs csrB (plain src indices, node-ordered
// within each bin) + nodeBeg/nodeCnt (absolute offsets into csrB).
// ---------------------------------------------------------------------------
__global__ __launch_bounds__(256) void regroup_kernel(
    const int* __restrict__ csrA, const int* __restrict__ gcntC,
    int* __restrict__ csrB, int* __restrict__ nodeBeg, int* __restrict__ nodeCnt,
    int N)
{
    __shared__ int h[CBIN], psum[CBIN], cur[CBIN];
    __shared__ int sorted[CAPC];               // 36.9 KB
    const int c = blockIdx.x, t = threadIdx.x;
    const int rbeg = c * CAPC;
    const int cnt = min(gcntC[c], CAPC);

    h[t] = 0;
    __syncthreads();
    for (int i = t; i < cnt; i += 256)
        atomicAdd(&h[csrA[(size_t)rbeg + i] & (CBIN - 1)], 1);
    __syncthreads();
    const int myCnt = h[t];
    psum[t] = myCnt;
    __syncthreads();
    for (int off = 1; off < 256; off <<= 1) {
        int v = (t >= off) ? psum[t - off] : 0;
        __syncthreads();
        if (t >= off) psum[t] += v;
        __syncthreads();
    }
    const int excl = psum[t] - myCnt;
    cur[t] = excl;
    {
        int node = (c << CSHIFT) + t;
        if (node < N) {
            nodeBeg[node] = rbeg + excl;
            nodeCnt[node] = myCnt;
        }
    }
    __syncthreads();
    for (int i = t; i < cnt; i += 256) {
        int p = csrA[(size_t)rbeg + i];
        int r = atomicAdd(&cur[p & (CBIN - 1)], 1);
        sorted[r] = p >> CSHIFT;
    }
    __syncthreads();
    for (int i = t; i < cnt; i += 256)
        csrB[(size_t)rbeg + i] = sorted[i];
}

// ---------------------------------------------------------------------------
// Fused aggregate + GEMM at 16-node granularity.
// P0': stage the group's contiguous, node-sorted csrB segment into LDS
//      (single coalesced burst; no sort needed).
// P1: gather: 4 waves x 4 nodes; half-wave edge split, uint4 loads
//     (8 bf16 cols/lane), fp32 acc, shfl_xor merge, bf16 row -> LDS A.
// P2: GEMM 16x256 @ 256x256 MFMA + bias + ReLU -> out (fp32).
// LDS ~14.7 KB.
// ---------------------------------------------------------------------------
__global__ __launch_bounds__(256) void agg_gemm_kernel(
    const unsigned short* __restrict__ fbf,
    const int* __restrict__ csrB,
    const int* __restrict__ nodeBeg,
    const int* __restrict__ nodeCnt,
    const unsigned short* __restrict__ Wt,
    const float* __restrict__ bias,
    float* __restrict__ out, int N)
{
    __shared__ int lsrc[CAPL];
    __shared__ int lBeg[TN], lCnt[TN];
    __shared__ int sB, sL, sFit;
    __shared__ unsigned short A[TN][D + 8];    // 8448 B

    const int blk  = blockIdx.x;
    const int t    = threadIdx.x;
    const int wave = t >> 6;
    const int lane = t & 63;
    const int sub  = lane & 31;
    const int half = lane >> 5;
    const int node0 = blk * TN;
    const size_t colOff = (size_t)(sub << 3);

    if (t < TN) {
        int node = node0 + t;
        bool valid = node < N;
        lBeg[t] = valid ? nodeBeg[node] : 0;
        lCnt[t] = valid ? nodeCnt[node] : 0;
    }
    __syncthreads();
    if (t == 0) {
        int lastL = min(TN - 1, N - 1 - node0);
        sB = lBeg[0];
        sL = lBeg[lastL] + lCnt[lastL] - lBeg[0];
        sFit = (sL <= CAPL);
    }
    __syncthreads();
    const int segB = sB, segL = sL, fit = sFit;
    if (fit) {
        for (int i = t; i < segL; i += 256)
            lsrc[i] = csrB[(size_t)segB + i];
    }
    __syncthreads();

    // ---- P1: gather 4 nodes per wave ----
    for (int ni = 0; ni < 4; ++ni) {
        const int l = (wave << 2) + ni;
        const int node = node0 + l;
        float a0 = 0.f, a1 = 0.f, a2 = 0.f, a3 = 0.f;
        float a4 = 0.f, a5 = 0.f, a6 = 0.f, a7 = 0.f;
        if (node < N) {
            const int* elist = fit ? lsrc : (csrB + segB);
            const int b0 = lBeg[l] - segB;
            const int c0 = lCnt[l];
            int j = 0;
            for (; j + 3 < c0; j += 4) {
                int s0 = elist[b0 + j + half];
                int s1 = elist[b0 + j + 2 + half];
                uint4 v0 = *reinterpret_cast<const uint4*>(fbf + ((size_t)s0 << 8) + colOff);
                uint4 v1 = *reinterpret_cast<const uint4*>(fbf + ((size_t)s1 << 8) + colOff);
                a0 += bf_lo(v0.x); a1 += bf_hi(v0.x); a2 += bf_lo(v0.y); a3 += bf_hi(v0.y);
                a4 += bf_lo(v0.z); a5 += bf_hi(v0.z); a6 += bf_lo(v0.w); a7 += bf_hi(v0.w);
                a0 += bf_lo(v1.x); a1 += bf_hi(v1.x); a2 += bf_lo(v1.y); a3 += bf_hi(v1.y);
                a4 += bf_lo(v1.z); a5 += bf_hi(v1.z); a6 += bf_lo(v1.w); a7 += bf_hi(v1.w);
            }
            if (j + 1 < c0) {
                int s0 = elist[b0 + j + half];
                uint4 v0 = *reinterpret_cast<const uint4*>(fbf + ((size_t)s0 << 8) + colOff);
                a0 += bf_lo(v0.x); a1 += bf_hi(v0.x); a2 += bf_lo(v0.y); a3 += bf_hi(v0.y);
                a4 += bf_lo(v0.z); a5 += bf_hi(v0.z); a6 += bf_lo(v0.w); a7 += bf_hi(v0.w);
                j += 2;
            }
            if (j < c0 && half == 0) {
                int s0 = elist[b0 + j];
                uint4 v0 = *reinterpret_cast<const uint4*>(fbf + ((size_t)s0 << 8) + colOff);
                a0 += bf_lo(v0.x); a1 += bf_hi(v0.x); a2 += bf_lo(v0.y); a3 += bf_hi(v0.y);
                a4 += bf_lo(v0.z); a5 += bf_hi(v0.z); a6 += bf_lo(v0.w); a7 += bf_hi(v0.w);
            }
        }
        a0 += __shfl_xor(a0, 32); a1 += __shfl_xor(a1, 32);
        a2 += __shfl_xor(a2, 32); a3 += __shfl_xor(a3, 32);
        a4 += __shfl_xor(a4, 32); a5 += __shfl_xor(a5, 32);
        a6 += __shfl_xor(a6, 32); a7 += __shfl_xor(a7, 32);
        if (half == 0) {
            uint4 r;
            r.x = (unsigned int)f2bf(a0) | ((unsigned int)f2bf(a1) << 16);
            r.y = (unsigned int)f2bf(a2) | ((unsigned int)f2bf(a3) << 16);
            r.z = (unsigned int)f2bf(a4) | ((unsigned int)f2bf(a5) << 16);
            r.w = (unsigned int)f2bf(a6) | ((unsigned int)f2bf(a7) << 16);
            *reinterpret_cast<uint4*>(&A[l][sub << 3]) = r;
        }
    }
    __syncthreads();

    // ---- P2: GEMM 16x256 ----
    const int lr = lane & 15;
    const int lg = lane >> 4;

    bf16x8 afr[8];
#pragma unroll
    for (int ks = 0; ks < 8; ++ks)
        afr[ks] = *reinterpret_cast<const bf16x8*>(&A[lr][ks * 32 + lg * 8]);

#pragma unroll
    for (int c = 0; c < 4; ++c) {
        const int ct = (wave << 2) + c;
        f32x4 acc = {0.f, 0.f, 0.f, 0.f};
        const unsigned short* bp = Wt + (size_t)(ct * 16 + lr) * D + lg * 8;
#pragma unroll
        for (int ks = 0; ks < 8; ++ks) {
            bf16x8 bfr = *reinterpret_cast<const bf16x8*>(bp + ks * 32);
            acc = __builtin_amdgcn_mfma_f32_16x16x32_bf16(afr[ks], bfr, acc, 0, 0, 0);
        }
        const float bv = bias[ct * 16 + lr];
#pragma unroll
        for (int jj = 0; jj < 4; ++jj) {
            int row = node0 + lg * 4 + jj;
            if (row < N) {
                float v = acc[jj] + bv;
                out[(size_t)row * D + ct * 16 + lr] = v > 0.f ? v : 0.f;
            }
        }
    }
}

// ---------------------------------------------------------------------------
// Fallback kernels (ws too small): direct atomic scatter + VALU linear.
// ---------------------------------------------------------------------------
__global__ __launch_bounds__(256) void scatter_kernel(
    const float* __restrict__ feature, const int* __restrict__ src,
    const int* __restrict__ dst, float* __restrict__ agg, int E)
{
    int edge = blockIdx.x * (blockDim.x >> 6) + (threadIdx.x >> 6);
    int lane = threadIdx.x & 63;
    if (edge >= E) return;
    int s = src[edge];
    int d = dst[edge];
    const float4 v = *reinterpret_cast<const float4*>(feature + (size_t)s * D + lane * 4);
    float* o = agg + (size_t)d * D + lane * 4;
    atomicAdd(o + 0, v.x);
    atomicAdd(o + 1, v.y);
    atomicAdd(o + 2, v.z);
    atomicAdd(o + 3, v.w);
}

#define BM 32
__global__ __launch_bounds__(256) void linear_relu_kernel(
    float* __restrict__ h, const float* __restrict__ W,
    const float* __restrict__ b, int n_nodes)
{
    __shared__ float sA[BM][D];
    const int node0 = blockIdx.x * BM;
    const int t = threadIdx.x;
    for (int m = 0; m < BM; ++m) {
        int nd = node0 + m;
        sA[m][t] = (nd < n_nodes) ? h[(size_t)nd * D + t] : 0.0f;
    }
    __syncthreads();
    float acc[BM];
#pragma unroll
    for (int m = 0; m < BM; ++m) acc[m] = 0.0f;
    for (int kk = 0; kk < D; ++kk) {
        float w = W[kk * D + t];
#pragma unroll
        for (int m = 0; m < BM; ++m) acc[m] += sA[m][kk] * w;
    }
    const float bias = b[t];
    for (int m = 0; m < BM; ++m) {
        int nd = node0 + m;
        if (nd < n_nodes) {
            float v = acc[m] + bias;
            h[(size_t)nd * D + t] = v > 0.0f ? v : 0.0f;
        }
    }
}

// ---------------------------------------------------------------------------
extern "C" void kernel_launch(void* const* d_in, const int* in_sizes, int n_in,
                              void* d_out, int out_size, void* d_ws, size_t ws_size,
                              hipStream_t stream)
{
    const float* feature = (const float*)d_in[0];
    const int*   src     = (const int*)d_in[1];
    const int*   dst     = (const int*)d_in[2];
    const float* W       = (const float*)d_in[3];
    const float* b       = (const float*)d_in[4];
    float*       out     = (float*)d_out;

    const int E = in_sizes[1];
    const int N = in_sizes[0] / D;
    const int NC = (N + CBIN - 1) >> CSHIFT;    // coarse bins
    const int chunk = (E + NB_P - 1) / NB_P;

    // ---- workspace layout -------------------------------------------------
    size_t off = 0;
    auto alloc = [&](size_t bytes, size_t align) {
        off = (off + align - 1) / align * align;
        size_t r = off; off += bytes; return r;
    };
    size_t o_gcntC = alloc((size_t)NC * 4, 16);
    size_t o_csrA  = alloc((size_t)NC * CAPC * 4, 16);
    size_t o_csrB  = alloc((size_t)NC * CAPC * 4, 16);
    size_t o_nbeg  = alloc((size_t)N * 4, 16);
    size_t o_ncnt  = alloc((size_t)N * 4, 16);
    size_t o_wt    = alloc((size_t)D * D * 2, 16);
    size_t o_fbf   = alloc((size_t)N * D * 2, 16);
    size_t need_full = off;

    char* ws = (char*)d_ws;

    // guards: bin capacity (mean + 8 sigma + 16) and bin count
    const double mc = (double)E / NC;
    const bool cap_ok =
        (mc + 8.0 * __builtin_sqrt(mc) + 16.0 <= (double)CAPC) &&
        (NC <= NCMAX);

    if (ws_size >= need_full && cap_ok) {
        int* gcntC   = (int*)(ws + o_gcntC);
        int* csrA    = (int*)(ws + o_csrA);
        int* csrB    = (int*)(ws + o_csrB);
        int* nodeBeg = (int*)(ws + o_nbeg);
        int* nodeCnt = (int*)(ws + o_ncnt);
        unsigned short* Wt  = (unsigned short*)(ws + o_wt);
        unsigned short* fbf = (unsigned short*)(ws + o_fbf);

        const long n8 = (long)N * D / 8;
        const int nConvF = (int)((n8 + 255) / 256);
        const int nConvW = (D * D / 4 + 255) / 256;

        hipMemsetAsync(gcntC, 0, (size_t)NC * 4, stream);

        part_kernel<<<NB_P + nConvF + nConvW, 256, 0, stream>>>(
            src, dst, gcntC, csrA, feature, fbf, n8, W, Wt,
            E, NC, chunk, nConvF);

        regroup_kernel<<<NC, 256, 0, stream>>>(
            csrA, gcntC, csrB, nodeBeg, nodeCnt, N);

        agg_gemm_kernel<<<(N + TN - 1) / TN, 256, 0, stream>>>(
            fbf, csrB, nodeBeg, nodeCnt, Wt, b, out, N);
    } else {
        hipMemsetAsync(d_out, 0, (size_t)out_size * sizeof(float), stream);
        scatter_kernel<<<(E + 3) / 4, 256, 0, stream>>>(feature, src, dst, out, E);
        linear_relu_kernel<<<(N + BM - 1) / BM, 256, 0, stream>>>(out, W, b, N);
    }
}

// Round 17
// 388.047 us; speedup vs baseline: 1.0957x; 1.0427x over previous
//
#include <hip/hip_runtime.h>

#define D 256
#define TN 16             // nodes per agg_gemm block
#define CSHIFT 8
#define CBIN 256          // nodes per coarse bin
#define NCMAX 512         // max coarse bins (pass-A LDS hist 2 KB)
#define CAPC 9216         // csr region per coarse bin (mean 8192)
#define NB_P 256          // pass-A scatter blocks
#define CAPL 1536         // LDS edge-list capacity per 16-node group (mean 512)

using bf16x8 = __attribute__((ext_vector_type(8))) short;
using f32x4  = __attribute__((ext_vector_type(4))) float;

__device__ inline float bf_lo(unsigned int u) {
    return __builtin_bit_cast(float, u << 16);
}
__device__ inline float bf_hi(unsigned int u) {
    return __builtin_bit_cast(float, u & 0xffff0000u);
}
__device__ inline unsigned short f2bf(float f) {
    unsigned int x = __builtin_bit_cast(unsigned int, f);
    unsigned int r = (x + 0x7fffu + ((x >> 16) & 1u)) >> 16;   // RNE
    return (unsigned short)r;
}

// ---------------------------------------------------------------------------
// Pass A: coarse scatter (dst>>8) || conv_feature || conv_w.
// ---------------------------------------------------------------------------
__global__ __launch_bounds__(256) void part_kernel(
    const int* __restrict__ src, const int* __restrict__ dst,
    int* __restrict__ gcntC, int* __restrict__ csrA,
    const float* __restrict__ feature, unsigned short* __restrict__ fbf, long n8,
    const float* __restrict__ W, unsigned short* __restrict__ Wt,
    int E, int NC, int chunk, int nConvF)
{
    __shared__ int h[NCMAX];
    const int b = blockIdx.x, t = threadIdx.x;

    if (b < NB_P) {
        for (int i = t; i < NC; i += 256) h[i] = 0;
        __syncthreads();
        const int beg = b * chunk;
        const int end = min(beg + chunk, E);
        for (int i = beg + t; i < end; i += 256)
            atomicAdd(&h[dst[i] >> CSHIFT], 1);
        __syncthreads();
        for (int i = t; i < NC; i += 256) {
            int c = h[i];
            h[i] = c ? atomicAdd(&gcntC[i], c) : 0;
        }
        __syncthreads();
        for (int i = beg + t; i < end; i += 256) {
            int d = dst[i];
            int c = d >> CSHIFT;
            int r = atomicAdd(&h[c], 1);
            if (r < CAPC)
                csrA[(size_t)c * CAPC + r] = (src[i] << CSHIFT) | (d & (CBIN - 1));
        }
        return;
    }
    if (b < NB_P + nConvF) {
        long i = (long)(b - NB_P) * 256 + t;
        if (i < n8) {
            const float4* p = reinterpret_cast<const float4*>(feature + i * 8);
            float4 v0 = p[0], v1 = p[1];
            uint4 r;
            r.x = (unsigned int)f2bf(v0.x) | ((unsigned int)f2bf(v0.y) << 16);
            r.y = (unsigned int)f2bf(v0.z) | ((unsigned int)f2bf(v0.w) << 16);
            r.z = (unsigned int)f2bf(v1.x) | ((unsigned int)f2bf(v1.y) << 16);
            r.w = (unsigned int)f2bf(v1.z) | ((unsigned int)f2bf(v1.w) << 16);
            *reinterpret_cast<uint4*>(fbf + i * 8) = r;
        }
        return;
    }
    int i = (b - NB_P - nConvF) * 256 + t;
    if (i < D * D / 4) {
        int n  = i >> 6;
        int k0 = (i & 63) * 4;
        float a  = W[(size_t)(k0 + 0) * D + n];
        float bb = W[(size_t)(k0 + 1) * D + n];
        float c  = W[(size_t)(k0 + 2) * D + n];
        float d  = W[(size_t)(k0 + 3) * D + n];
        uint2 r;
        r.x = (unsigned int)f2bf(a) | ((unsigned int)f2bf(bb) << 16);
        r.y = (unsigned int)f2bf(c) | ((unsigned int)f2bf(d) << 16);
        *reinterpret_cast<uint2*>(Wt + (size_t)n * D + k0) = r;
    }
}

// ---------------------------------------------------------------------------
// Pass B: per-bin full node sort (256-key LDS counting sort).
// Outputs csrB (plain src indices, node-ordered within each bin) +
// nodeBeg/nodeCnt (absolute offsets into csrB).
// ---------------------------------------------------------------------------
__global__ __launch_bounds__(256) void regroup_kernel(
    const int* __restrict__ csrA, const int* __restrict__ gcntC,
    int* __restrict__ csrB, int* __restrict__ nodeBeg, int* __restrict__ nodeCnt,
    int N)
{
    __shared__ int h[CBIN], psum[CBIN], cur[CBIN];
    __shared__ int sorted[CAPC];               // 36.9 KB
    const int c = blockIdx.x, t = threadIdx.x;
    const int rbeg = c * CAPC;
    const int cnt = min(gcntC[c], CAPC);

    h[t] = 0;
    __syncthreads();
    for (int i = t; i < cnt; i += 256)
        atomicAdd(&h[csrA[(size_t)rbeg + i] & (CBIN - 1)], 1);
    __syncthreads();
    const int myCnt = h[t];
    psum[t] = myCnt;
    __syncthreads();
    for (int off = 1; off < 256; off <<= 1) {
        int v = (t >= off) ? psum[t - off] : 0;
        __syncthreads();
        if (t >= off) psum[t] += v;
        __syncthreads();
    }
    const int excl = psum[t] - myCnt;
    cur[t] = excl;
    {
        int node = (c << CSHIFT) + t;
        if (node < N) {
            nodeBeg[node] = rbeg + excl;
            nodeCnt[node] = myCnt;
        }
    }
    __syncthreads();
    for (int i = t; i < cnt; i += 256) {
        int p = csrA[(size_t)rbeg + i];
        int r = atomicAdd(&cur[p & (CBIN - 1)], 1);
        sorted[r] = p >> CSHIFT;
    }
    __syncthreads();
    for (int i = t; i < cnt; i += 256)
        csrB[(size_t)rbeg + i] = sorted[i];
}

// ---------------------------------------------------------------------------
// Fused aggregate + GEMM at 16-node granularity.
// P0': coalesced burst copy of the group's contiguous node-sorted csrB
//      segment into LDS (no sort).
// P1: gather with the edge list in a SINGLE address space per path:
//     hot path reads lsrc[] (LDS -> ds_read), cold path (segment > CAPL,
//     ~45-sigma never) reads csrB directly. No mixed-address-space pointer,
//     so no flat-load pessimization.
// P2: GEMM 16x256 @ 256x256 MFMA + bias + ReLU -> out (fp32).
// ---------------------------------------------------------------------------
#define GATHER_NODE(ELIST)                                                        \
    {                                                                             \
        int j = 0;                                                                \
        for (; j + 3 < c0; j += 4) {                                              \
            int s0 = (ELIST)[b0 + j + half];                                      \
            int s1 = (ELIST)[b0 + j + 2 + half];                                  \
            uint4 v0 = *reinterpret_cast<const uint4*>(fbf + ((size_t)s0 << 8) + colOff); \
            uint4 v1 = *reinterpret_cast<const uint4*>(fbf + ((size_t)s1 << 8) + colOff); \
            a0 += bf_lo(v0.x); a1 += bf_hi(v0.x); a2 += bf_lo(v0.y); a3 += bf_hi(v0.y); \
            a4 += bf_lo(v0.z); a5 += bf_hi(v0.z); a6 += bf_lo(v0.w); a7 += bf_hi(v0.w); \
            a0 += bf_lo(v1.x); a1 += bf_hi(v1.x); a2 += bf_lo(v1.y); a3 += bf_hi(v1.y); \
            a4 += bf_lo(v1.z); a5 += bf_hi(v1.z); a6 += bf_lo(v1.w); a7 += bf_hi(v1.w); \
        }                                                                         \
        if (j + 1 < c0) {                                                         \
            int s0 = (ELIST)[b0 + j + half];                                      \
            uint4 v0 = *reinterpret_cast<const uint4*>(fbf + ((size_t)s0 << 8) + colOff); \
            a0 += bf_lo(v0.x); a1 += bf_hi(v0.x); a2 += bf_lo(v0.y); a3 += bf_hi(v0.y); \
            a4 += bf_lo(v0.z); a5 += bf_hi(v0.z); a6 += bf_lo(v0.w); a7 += bf_hi(v0.w); \
            j += 2;                                                               \
        }                                                                         \
        if (j < c0 && half == 0) {                                                \
            int s0 = (ELIST)[b0 + j];                                             \
            uint4 v0 = *reinterpret_cast<const uint4*>(fbf + ((size_t)s0 << 8) + colOff); \
            a0 += bf_lo(v0.x); a1 += bf_hi(v0.x); a2 += bf_lo(v0.y); a3 += bf_hi(v0.y); \
            a4 += bf_lo(v0.z); a5 += bf_hi(v0.z); a6 += bf_lo(v0.w); a7 += bf_hi(v0.w); \
        }                                                                         \
    }

__global__ __launch_bounds__(256) void agg_gemm_kernel(
    const unsigned short* __restrict__ fbf,
    const int* __restrict__ csrB,
    const int* __restrict__ nodeBeg,
    const int* __restrict__ nodeCnt,
    const unsigned short* __restrict__ Wt,
    const float* __restrict__ bias,
    float* __restrict__ out, int N)
{
    __shared__ int lsrc[CAPL];
    __shared__ int lBeg[TN], lCnt[TN];
    __shared__ int sB, sL, sFit;
    __shared__ unsigned short A[TN][D + 8];    // 8448 B

    const int blk  = blockIdx.x;
    const int t    = threadIdx.x;
    const int wave = t >> 6;
    const int lane = t & 63;
    const int sub  = lane & 31;
    const int half = lane >> 5;
    const int node0 = blk * TN;
    const size_t colOff = (size_t)(sub << 3);

    if (t < TN) {
        int node = node0 + t;
        bool valid = node < N;
        lBeg[t] = valid ? nodeBeg[node] : 0;
        lCnt[t] = valid ? nodeCnt[node] : 0;
    }
    __syncthreads();
    if (t == 0) {
        int lastL = min(TN - 1, N - 1 - node0);
        sB = lBeg[0];
        sL = lBeg[lastL] + lCnt[lastL] - lBeg[0];
        sFit = (sL <= CAPL);
    }
    __syncthreads();
    const int segB = sB, segL = sL, fit = sFit;
    if (fit) {
        for (int i = t; i < segL; i += 256)
            lsrc[i] = csrB[(size_t)segB + i];
    }
    __syncthreads();

    // ---- P1: gather 4 nodes per wave ----
    for (int ni = 0; ni < 4; ++ni) {
        const int l = (wave << 2) + ni;
        const int node = node0 + l;
        float a0 = 0.f, a1 = 0.f, a2 = 0.f, a3 = 0.f;
        float a4 = 0.f, a5 = 0.f, a6 = 0.f, a7 = 0.f;
        if (node < N) {
            const int b0 = lBeg[l] - segB;
            const int c0 = lCnt[l];
            if (fit) {
                GATHER_NODE(lsrc)                      // LDS path: ds_read
            } else {
                const int* gsrc = csrB + segB;
                GATHER_NODE(gsrc)                      // global path
            }
        }
        a0 += __shfl_xor(a0, 32); a1 += __shfl_xor(a1, 32);
        a2 += __shfl_xor(a2, 32); a3 += __shfl_xor(a3, 32);
        a4 += __shfl_xor(a4, 32); a5 += __shfl_xor(a5, 32);
        a6 += __shfl_xor(a6, 32); a7 += __shfl_xor(a7, 32);
        if (half == 0) {
            uint4 r;
            r.x = (unsigned int)f2bf(a0) | ((unsigned int)f2bf(a1) << 16);
            r.y = (unsigned int)f2bf(a2) | ((unsigned int)f2bf(a3) << 16);
            r.z = (unsigned int)f2bf(a4) | ((unsigned int)f2bf(a5) << 16);
            r.w = (unsigned int)f2bf(a6) | ((unsigned int)f2bf(a7) << 16);
            *reinterpret_cast<uint4*>(&A[l][sub << 3]) = r;
        }
    }
    __syncthreads();

    // ---- P2: GEMM 16x256 ----
    const int lr = lane & 15;
    const int lg = lane >> 4;

    bf16x8 afr[8];
#pragma unroll
    for (int ks = 0; ks < 8; ++ks)
        afr[ks] = *reinterpret_cast<const bf16x8*>(&A[lr][ks * 32 + lg * 8]);

#pragma unroll
    for (int c = 0; c < 4; ++c) {
        const int ct = (wave << 2) + c;
        f32x4 acc = {0.f, 0.f, 0.f, 0.f};
        const unsigned short* bp = Wt + (size_t)(ct * 16 + lr) * D + lg * 8;
#pragma unroll
        for (int ks = 0; ks < 8; ++ks) {
            bf16x8 bfr = *reinterpret_cast<const bf16x8*>(bp + ks * 32);
            acc = __builtin_amdgcn_mfma_f32_16x16x32_bf16(afr[ks], bfr, acc, 0, 0, 0);
        }
        const float bv = bias[ct * 16 + lr];
#pragma unroll
        for (int jj = 0; jj < 4; ++jj) {
            int row = node0 + lg * 4 + jj;
            if (row < N) {
                float v = acc[jj] + bv;
                out[(size_t)row * D + ct * 16 + lr] = v > 0.f ? v : 0.f;
            }
        }
    }
}

// ---------------------------------------------------------------------------
// Fallback kernels (ws too small): direct atomic scatter + VALU linear.
// ---------------------------------------------------------------------------
__global__ __launch_bounds__(256) void scatter_kernel(
    const float* __restrict__ feature, const int* __restrict__ src,
    const int* __restrict__ dst, float* __restrict__ agg, int E)
{
    int edge = blockIdx.x * (blockDim.x >> 6) + (threadIdx.x >> 6);
    int lane = threadIdx.x & 63;
    if (edge >= E) return;
    int s = src[edge];
    int d = dst[edge];
    const float4 v = *reinterpret_cast<const float4*>(feature + (size_t)s * D + lane * 4);
    float* o = agg + (size_t)d * D + lane * 4;
    atomicAdd(o + 0, v.x);
    atomicAdd(o + 1, v.y);
    atomicAdd(o + 2, v.z);
    atomicAdd(o + 3, v.w);
}

#define BM 32
__global__ __launch_bounds__(256) void linear_relu_kernel(
    float* __restrict__ h, const float* __restrict__ W,
    const float* __restrict__ b, int n_nodes)
{
    __shared__ float sA[BM][D];
    const int node0 = blockIdx.x * BM;
    const int t = threadIdx.x;
    for (int m = 0; m < BM; ++m) {
        int nd = node0 + m;
        sA[m][t] = (nd < n_nodes) ? h[(size_t)nd * D + t] : 0.0f;
    }
    __syncthreads();
    float acc[BM];
#pragma unroll
    for (int m = 0; m < BM; ++m) acc[m] = 0.0f;
    for (int kk = 0; kk < D; ++kk) {
        float w = W[kk * D + t];
#pragma unroll
        for (int m = 0; m < BM; ++m) acc[m] += sA[m][kk] * w;
    }
    const float bias = b[t];
    for (int m = 0; m < BM; ++m) {
        int nd = node0 + m;
        if (nd < n_nodes) {
            float v = acc[m] + bias;
            h[(size_t)nd * D + t] = v > 0.0f ? v : 0.0f;
        }
    }
}

// ---------------------------------------------------------------------------
extern "C" void kernel_launch(void* const* d_in, const int* in_sizes, int n_in,
                              void* d_out, int out_size, void* d_ws, size_t ws_size,
                              hipStream_t stream)
{
    const float* feature = (const float*)d_in[0];
    const int*   src     = (const int*)d_in[1];
    const int*   dst     = (const int*)d_in[2];
    const float* W       = (const float*)d_in[3];
    const float* b       = (const float*)d_in[4];
    float*       out     = (float*)d_out;

    const int E = in_sizes[1];
    const int N = in_sizes[0] / D;
    const int NC = (N + CBIN - 1) >> CSHIFT;    // coarse bins
    const int chunk = (E + NB_P - 1) / NB_P;

    // ---- workspace layout -------------------------------------------------
    size_t off = 0;
    auto alloc = [&](size_t bytes, size_t align) {
        off = (off + align - 1) / align * align;
        size_t r = off; off += bytes; return r;
    };
    size_t o_gcntC = alloc((size_t)NC * 4, 16);
    size_t o_csrA  = alloc((size_t)NC * CAPC * 4, 16);
    size_t o_csrB  = alloc((size_t)NC * CAPC * 4, 16);
    size_t o_nbeg  = alloc((size_t)N * 4, 16);
    size_t o_ncnt  = alloc((size_t)N * 4, 16);
    size_t o_wt    = alloc((size_t)D * D * 2, 16);
    size_t o_fbf   = alloc((size_t)N * D * 2, 16);
    size_t need_full = off;

    char* ws = (char*)d_ws;

    // guards: bin capacity (mean + 8 sigma + 16) and bin count
    const double mc = (double)E / NC;
    const bool cap_ok =
        (mc + 8.0 * __builtin_sqrt(mc) + 16.0 <= (double)CAPC) &&
        (NC <= NCMAX);

    if (ws_size >= need_full && cap_ok) {
        int* gcntC   = (int*)(ws + o_gcntC);
        int* csrA    = (int*)(ws + o_csrA);
        int* csrB    = (int*)(ws + o_csrB);
        int* nodeBeg = (int*)(ws + o_nbeg);
        int* nodeCnt = (int*)(ws + o_ncnt);
        unsigned short* Wt  = (unsigned short*)(ws + o_wt);
        unsigned short* fbf = (unsigned short*)(ws + o_fbf);

        const long n8 = (long)N * D / 8;
        const int nConvF = (int)((n8 + 255) / 256);
        const int nConvW = (D * D / 4 + 255) / 256;

        hipMemsetAsync(gcntC, 0, (size_t)NC * 4, stream);

        part_kernel<<<NB_P + nConvF + nConvW, 256, 0, stream>>>(
            src, dst, gcntC, csrA, feature, fbf, n8, W, Wt,
            E, NC, chunk, nConvF);

        regroup_kernel<<<NC, 256, 0, stream>>>(
            csrA, gcntC, csrB, nodeBeg, nodeCnt, N);

        agg_gemm_kernel<<<(N + TN - 1) / TN, 256, 0, stream>>>(
            fbf, csrB, nodeBeg, nodeCnt, Wt, b, out, N);
    } else {
        hipMemsetAsync(d_out, 0, (size_t)out_size * sizeof(float), stream);
        scatter_kernel<<<(E + 3) / 4, 256, 0, stream>>>(feature, src, dst, out, E);
        linear_relu_kernel<<<(N + BM - 1) / BM, 256, 0, stream>>>(out, W, b, N);
    }
}

// Round 18
// 385.254 us; speedup vs baseline: 1.1037x; 1.0073x over previous
//
#include <hip/hip_runtime.h>

#define D 256
#define TN 16             // nodes per agg_gemm block
#define CSHIFT 8
#define CBIN 256          // nodes per coarse bin
#define NCMAX 512         // max coarse bins (pass-A LDS hist 2 KB)
#define CAPC 9216         // csr region per coarse bin (mean 8192)
#define NB_P 512          // pass-A scatter blocks (512: halve serial chunk)
#define CAPL 1536         // LDS edge-list capacity per 16-node group (mean 512)

using bf16x8 = __attribute__((ext_vector_type(8))) short;
using f32x4  = __attribute__((ext_vector_type(4))) float;

__device__ inline float bf_lo(unsigned int u) {
    return __builtin_bit_cast(float, u << 16);
}
__device__ inline float bf_hi(unsigned int u) {
    return __builtin_bit_cast(float, u & 0xffff0000u);
}
__device__ inline unsigned short f2bf(float f) {
    unsigned int x = __builtin_bit_cast(unsigned int, f);
    unsigned int r = (x + 0x7fffu + ((x >> 16) & 1u)) >> 16;   // RNE
    return (unsigned short)r;
}

// ---------------------------------------------------------------------------
// Pass A: coarse scatter (dst>>8) || conv_feature || conv_w.
// ---------------------------------------------------------------------------
__global__ __launch_bounds__(256) void part_kernel(
    const int* __restrict__ src, const int* __restrict__ dst,
    int* __restrict__ gcntC, int* __restrict__ csrA,
    const float* __restrict__ feature, unsigned short* __restrict__ fbf, long n8,
    const float* __restrict__ W, unsigned short* __restrict__ Wt,
    int E, int NC, int chunk, int nConvF)
{
    __shared__ int h[NCMAX];
    const int b = blockIdx.x, t = threadIdx.x;

    if (b < NB_P) {
        for (int i = t; i < NC; i += 256) h[i] = 0;
        __syncthreads();
        const int beg = b * chunk;
        const int end = min(beg + chunk, E);
        for (int i = beg + t; i < end; i += 256)
            atomicAdd(&h[dst[i] >> CSHIFT], 1);
        __syncthreads();
        for (int i = t; i < NC; i += 256) {
            int c = h[i];
            h[i] = c ? atomicAdd(&gcntC[i], c) : 0;
        }
        __syncthreads();
        for (int i = beg + t; i < end; i += 256) {
            int d = dst[i];
            int c = d >> CSHIFT;
            int r = atomicAdd(&h[c], 1);
            if (r < CAPC)
                csrA[(size_t)c * CAPC + r] = (src[i] << CSHIFT) | (d & (CBIN - 1));
        }
        return;
    }
    if (b < NB_P + nConvF) {
        long i = (long)(b - NB_P) * 256 + t;
        if (i < n8) {
            const float4* p = reinterpret_cast<const float4*>(feature + i * 8);
            float4 v0 = p[0], v1 = p[1];
            uint4 r;
            r.x = (unsigned int)f2bf(v0.x) | ((unsigned int)f2bf(v0.y) << 16);
            r.y = (unsigned int)f2bf(v0.z) | ((unsigned int)f2bf(v0.w) << 16);
            r.z = (unsigned int)f2bf(v1.x) | ((unsigned int)f2bf(v1.y) << 16);
            r.w = (unsigned int)f2bf(v1.z) | ((unsigned int)f2bf(v1.w) << 16);
            *reinterpret_cast<uint4*>(fbf + i * 8) = r;
        }
        return;
    }
    int i = (b - NB_P - nConvF) * 256 + t;
    if (i < D * D / 4) {
        int n  = i >> 6;
        int k0 = (i & 63) * 4;
        float a  = W[(size_t)(k0 + 0) * D + n];
        float bb = W[(size_t)(k0 + 1) * D + n];
        float c  = W[(size_t)(k0 + 2) * D + n];
        float d  = W[(size_t)(k0 + 3) * D + n];
        uint2 r;
        r.x = (unsigned int)f2bf(a) | ((unsigned int)f2bf(bb) << 16);
        r.y = (unsigned int)f2bf(c) | ((unsigned int)f2bf(d) << 16);
        *reinterpret_cast<uint2*>(Wt + (size_t)n * D + k0) = r;
    }
}

// ---------------------------------------------------------------------------
// Pass B: per-bin full node sort (256-key LDS counting sort).
// Outputs csrB (plain src indices, node-ordered within each bin) +
// nodeBeg/nodeCnt (absolute offsets into csrB).
// ---------------------------------------------------------------------------
__global__ __launch_bounds__(256) void regroup_kernel(
    const int* __restrict__ csrA, const int* __restrict__ gcntC,
    int* __restrict__ csrB, int* __restrict__ nodeBeg, int* __restrict__ nodeCnt,
    int N)
{
    __shared__ int h[CBIN], psum[CBIN], cur[CBIN];
    __shared__ int sorted[CAPC];               // 36.9 KB
    const int c = blockIdx.x, t = threadIdx.x;
    const int rbeg = c * CAPC;
    const int cnt = min(gcntC[c], CAPC);

    h[t] = 0;
    __syncthreads();
    for (int i = t; i < cnt; i += 256)
        atomicAdd(&h[csrA[(size_t)rbeg + i] & (CBIN - 1)], 1);
    __syncthreads();
    const int myCnt = h[t];
    psum[t] = myCnt;
    __syncthreads();
    for (int off = 1; off < 256; off <<= 1) {
        int v = (t >= off) ? psum[t - off] : 0;
        __syncthreads();
        if (t >= off) psum[t] += v;
        __syncthreads();
    }
    const int excl = psum[t] - myCnt;
    cur[t] = excl;
    {
        int node = (c << CSHIFT) + t;
        if (node < N) {
            nodeBeg[node] = rbeg + excl;
            nodeCnt[node] = myCnt;
        }
    }
    __syncthreads();
    for (int i = t; i < cnt; i += 256) {
        int p = csrA[(size_t)rbeg + i];
        int r = atomicAdd(&cur[p & (CBIN - 1)], 1);
        sorted[r] = p >> CSHIFT;
    }
    __syncthreads();
    for (int i = t; i < cnt; i += 256)
        csrB[(size_t)rbeg + i] = sorted[i];
}

// ---------------------------------------------------------------------------
// Fused aggregate + GEMM at 16-node granularity.
// P0': coalesced burst copy of the group's contiguous node-sorted csrB
//      segment into LDS.
// P1: gather with the edge list in a SINGLE address space per path (no
//     mixed-address-space pointer -> no flat-load pessimization).
// P2: GEMM 16x256 @ 256x256 MFMA + bias + ReLU -> out (fp32).
// ---------------------------------------------------------------------------
#define GATHER_NODE(ELIST)                                                        \
    {                                                                             \
        int j = 0;                                                                \
        for (; j + 3 < c0; j += 4) {                                              \
            int s0 = (ELIST)[b0 + j + half];                                      \
            int s1 = (ELIST)[b0 + j + 2 + half];                                  \
            uint4 v0 = *reinterpret_cast<const uint4*>(fbf + ((size_t)s0 << 8) + colOff); \
            uint4 v1 = *reinterpret_cast<const uint4*>(fbf + ((size_t)s1 << 8) + colOff); \
            a0 += bf_lo(v0.x); a1 += bf_hi(v0.x); a2 += bf_lo(v0.y); a3 += bf_hi(v0.y); \
            a4 += bf_lo(v0.z); a5 += bf_hi(v0.z); a6 += bf_lo(v0.w); a7 += bf_hi(v0.w); \
            a0 += bf_lo(v1.x); a1 += bf_hi(v1.x); a2 += bf_lo(v1.y); a3 += bf_hi(v1.y); \
            a4 += bf_lo(v1.z); a5 += bf_hi(v1.z); a6 += bf_lo(v1.w); a7 += bf_hi(v1.w); \
        }                                                                         \
        if (j + 1 < c0) {                                                         \
            int s0 = (ELIST)[b0 + j + half];                                      \
            uint4 v0 = *reinterpret_cast<const uint4*>(fbf + ((size_t)s0 << 8) + colOff); \
            a0 += bf_lo(v0.x); a1 += bf_hi(v0.x); a2 += bf_lo(v0.y); a3 += bf_hi(v0.y); \
            a4 += bf_lo(v0.z); a5 += bf_hi(v0.z); a6 += bf_lo(v0.w); a7 += bf_hi(v0.w); \
            j += 2;                                                               \
        }                                                                         \
        if (j < c0 && half == 0) {                                                \
            int s0 = (ELIST)[b0 + j];                                             \
            uint4 v0 = *reinterpret_cast<const uint4*>(fbf + ((size_t)s0 << 8) + colOff); \
            a0 += bf_lo(v0.x); a1 += bf_hi(v0.x); a2 += bf_lo(v0.y); a3 += bf_hi(v0.y); \
            a4 += bf_lo(v0.z); a5 += bf_hi(v0.z); a6 += bf_lo(v0.w); a7 += bf_hi(v0.w); \
        }                                                                         \
    }

__global__ __launch_bounds__(256) void agg_gemm_kernel(
    const unsigned short* __restrict__ fbf,
    const int* __restrict__ csrB,
    const int* __restrict__ nodeBeg,
    const int* __restrict__ nodeCnt,
    const unsigned short* __restrict__ Wt,
    const float* __restrict__ bias,
    float* __restrict__ out, int N)
{
    __shared__ int lsrc[CAPL];
    __shared__ int lBeg[TN], lCnt[TN];
    __shared__ int sB, sL, sFit;
    __shared__ unsigned short A[TN][D + 8];    // 8448 B

    const int blk  = blockIdx.x;
    const int t    = threadIdx.x;
    const int wave = t >> 6;
    const int lane = t & 63;
    const int sub  = lane & 31;
    const int half = lane >> 5;
    const int node0 = blk * TN;
    const size_t colOff = (size_t)(sub << 3);

    if (t < TN) {
        int node = node0 + t;
        bool valid = node < N;
        lBeg[t] = valid ? nodeBeg[node] : 0;
        lCnt[t] = valid ? nodeCnt[node] : 0;
    }
    __syncthreads();
    if (t == 0) {
        int lastL = min(TN - 1, N - 1 - node0);
        sB = lBeg[0];
        sL = lBeg[lastL] + lCnt[lastL] - lBeg[0];
        sFit = (sL <= CAPL);
    }
    __syncthreads();
    const int segB = sB, segL = sL, fit = sFit;
    if (fit) {
        for (int i = t; i < segL; i += 256)
            lsrc[i] = csrB[(size_t)segB + i];
    }
    __syncthreads();

    // ---- P1: gather 4 nodes per wave ----
    for (int ni = 0; ni < 4; ++ni) {
        const int l = (wave << 2) + ni;
        const int node = node0 + l;
        float a0 = 0.f, a1 = 0.f, a2 = 0.f, a3 = 0.f;
        float a4 = 0.f, a5 = 0.f, a6 = 0.f, a7 = 0.f;
        if (node < N) {
            const int b0 = lBeg[l] - segB;
            const int c0 = lCnt[l];
            if (fit) {
                GATHER_NODE(lsrc)                      // LDS path: ds_read
            } else {
                const int* gsrc = csrB + segB;
                GATHER_NODE(gsrc)                      // global path
            }
        }
        a0 += __shfl_xor(a0, 32); a1 += __shfl_xor(a1, 32);
        a2 += __shfl_xor(a2, 32); a3 += __shfl_xor(a3, 32);
        a4 += __shfl_xor(a4, 32); a5 += __shfl_xor(a5, 32);
        a6 += __shfl_xor(a6, 32); a7 += __shfl_xor(a7, 32);
        if (half == 0) {
            uint4 r;
            r.x = (unsigned int)f2bf(a0) | ((unsigned int)f2bf(a1) << 16);
            r.y = (unsigned int)f2bf(a2) | ((unsigned int)f2bf(a3) << 16);
            r.z = (unsigned int)f2bf(a4) | ((unsigned int)f2bf(a5) << 16);
            r.w = (unsigned int)f2bf(a6) | ((unsigned int)f2bf(a7) << 16);
            *reinterpret_cast<uint4*>(&A[l][sub << 3]) = r;
        }
    }
    __syncthreads();

    // ---- P2: GEMM 16x256 ----
    const int lr = lane & 15;
    const int lg = lane >> 4;

    bf16x8 afr[8];
#pragma unroll
    for (int ks = 0; ks < 8; ++ks)
        afr[ks] = *reinterpret_cast<const bf16x8*>(&A[lr][ks * 32 + lg * 8]);

#pragma unroll
    for (int c = 0; c < 4; ++c) {
        const int ct = (wave << 2) + c;
        f32x4 acc = {0.f, 0.f, 0.f, 0.f};
        const unsigned short* bp = Wt + (size_t)(ct * 16 + lr) * D + lg * 8;
#pragma unroll
        for (int ks = 0; ks < 8; ++ks) {
            bf16x8 bfr = *reinterpret_cast<const bf16x8*>(bp + ks * 32);
            acc = __builtin_amdgcn_mfma_f32_16x16x32_bf16(afr[ks], bfr, acc, 0, 0, 0);
        }
        const float bv = bias[ct * 16 + lr];
#pragma unroll
        for (int jj = 0; jj < 4; ++jj) {
            int row = node0 + lg * 4 + jj;
            if (row < N) {
                float v = acc[jj] + bv;
                out[(size_t)row * D + ct * 16 + lr] = v > 0.f ? v : 0.f;
            }
        }
    }
}

// ---------------------------------------------------------------------------
// Fallback kernels (ws too small): direct atomic scatter + VALU linear.
// ---------------------------------------------------------------------------
__global__ __launch_bounds__(256) void scatter_kernel(
    const float* __restrict__ feature, const int* __restrict__ src,
    const int* __restrict__ dst, float* __restrict__ agg, int E)
{
    int edge = blockIdx.x * (blockDim.x >> 6) + (threadIdx.x >> 6);
    int lane = threadIdx.x & 63;
    if (edge >= E) return;
    int s = src[edge];
    int d = dst[edge];
    const float4 v = *reinterpret_cast<const float4*>(feature + (size_t)s * D + lane * 4);
    float* o = agg + (size_t)d * D + lane * 4;
    atomicAdd(o + 0, v.x);
    atomicAdd(o + 1, v.y);
    atomicAdd(o + 2, v.z);
    atomicAdd(o + 3, v.w);
}

#define BM 32
__global__ __launch_bounds__(256) void linear_relu_kernel(
    float* __restrict__ h, const float* __restrict__ W,
    const float* __restrict__ b, int n_nodes)
{
    __shared__ float sA[BM][D];
    const int node0 = blockIdx.x * BM;
    const int t = threadIdx.x;
    for (int m = 0; m < BM; ++m) {
        int nd = node0 + m;
        sA[m][t] = (nd < n_nodes) ? h[(size_t)nd * D + t] : 0.0f;
    }
    __syncthreads();
    float acc[BM];
#pragma unroll
    for (int m = 0; m < BM; ++m) acc[m] = 0.0f;
    for (int kk = 0; kk < D; ++kk) {
        float w = W[kk * D + t];
#pragma unroll
        for (int m = 0; m < BM; ++m) acc[m] += sA[m][kk] * w;
    }
    const float bias = b[t];
    for (int m = 0; m < BM; ++m) {
        int nd = node0 + m;
        if (nd < n_nodes) {
            float v = acc[m] + bias;
            h[(size_t)nd * D + t] = v > 0.0f ? v : 0.0f;
        }
    }
}

// ---------------------------------------------------------------------------
extern "C" void kernel_launch(void* const* d_in, const int* in_sizes, int n_in,
                              void* d_out, int out_size, void* d_ws, size_t ws_size,
                              hipStream_t stream)
{
    const float* feature = (const float*)d_in[0];
    const int*   src     = (const int*)d_in[1];
    const int*   dst     = (const int*)d_in[2];
    const float* W       = (const float*)d_in[3];
    const float* b       = (const float*)d_in[4];
    float*       out     = (float*)d_out;

    const int E = in_sizes[1];
    const int N = in_sizes[0] / D;
    const int NC = (N + CBIN - 1) >> CSHIFT;    // coarse bins
    const int chunk = (E + NB_P - 1) / NB_P;

    // ---- workspace layout -------------------------------------------------
    size_t off = 0;
    auto alloc = [&](size_t bytes, size_t align) {
        off = (off + align - 1) / align * align;
        size_t r = off; off += bytes; return r;
    };
    size_t o_gcntC = alloc((size_t)NC * 4, 16);
    size_t o_csrA  = alloc((size_t)NC * CAPC * 4, 16);
    size_t o_csrB  = alloc((size_t)NC * CAPC * 4, 16);
    size_t o_nbeg  = alloc((size_t)N * 4, 16);
    size_t o_ncnt  = alloc((size_t)N * 4, 16);
    size_t o_wt    = alloc((size_t)D * D * 2, 16);
    size_t o_fbf   = alloc((size_t)N * D * 2, 16);
    size_t need_full = off;

    char* ws = (char*)d_ws;

    // guards: bin capacity (mean + 8 sigma + 16) and bin count
    const double mc = (double)E / NC;
    const bool cap_ok =
        (mc + 8.0 * __builtin_sqrt(mc) + 16.0 <= (double)CAPC) &&
        (NC <= NCMAX);

    if (ws_size >= need_full && cap_ok) {
        int* gcntC   = (int*)(ws + o_gcntC);
        int* csrA    = (int*)(ws + o_csrA);
        int* csrB    = (int*)(ws + o_csrB);
        int* nodeBeg = (int*)(ws + o_nbeg);
        int* nodeCnt = (int*)(ws + o_ncnt);
        unsigned short* Wt  = (unsigned short*)(ws + o_wt);
        unsigned short* fbf = (unsigned short*)(ws + o_fbf);

        const long n8 = (long)N * D / 8;
        const int nConvF = (int)((n8 + 255) / 256);
        const int nConvW = (D * D / 4 + 255) / 256;

        hipMemsetAsync(gcntC, 0, (size_t)NC * 4, stream);

        part_kernel<<<NB_P + nConvF + nConvW, 256, 0, stream>>>(
            src, dst, gcntC, csrA, feature, fbf, n8, W, Wt,
            E, NC, chunk, nConvF);

        regroup_kernel<<<NC, 256, 0, stream>>>(
            csrA, gcntC, csrB, nodeBeg, nodeCnt, N);

        agg_gemm_kernel<<<(N + TN - 1) / TN, 256, 0, stream>>>(
            fbf, csrB, nodeBeg, nodeCnt, Wt, b, out, N);
    } else {
        hipMemsetAsync(d_out, 0, (size_t)out_size * sizeof(float), stream);
        scatter_kernel<<<(E + 3) / 4, 256, 0, stream>>>(feature, src, dst, out, E);
        linear_relu_kernel<<<(N + BM - 1) / BM, 256, 0, stream>>>(out, W, b, N);
    }
}

// Round 19
// 377.052 us; speedup vs baseline: 1.1277x; 1.0218x over previous
//
#include <hip/hip_runtime.h>

#define D 256
#define TN 16             // nodes per agg_gemm block
#define CSHIFT 8
#define CBIN 256          // nodes per coarse bin
#define NCMAX 512         // max coarse bins (pass-A LDS hist 2 KB)
#define CAPC 9216         // csr region per coarse bin (mean 8192)
#define NB_P 512          // pass-A scatter blocks
#define CAPL 1536         // LDS edge-list capacity per 16-node group (mean 512)

using bf16x8 = __attribute__((ext_vector_type(8))) short;
using f32x4  = __attribute__((ext_vector_type(4))) float;

__device__ inline float bf_lo(unsigned int u) {
    return __builtin_bit_cast(float, u << 16);
}
__device__ inline float bf_hi(unsigned int u) {
    return __builtin_bit_cast(float, u & 0xffff0000u);
}
__device__ inline unsigned short f2bf(float f) {
    unsigned int x = __builtin_bit_cast(unsigned int, f);
    unsigned int r = (x + 0x7fffu + ((x >> 16) & 1u)) >> 16;   // RNE
    return (unsigned short)r;
}

// ---------------------------------------------------------------------------
// Pass A: coarse scatter (dst>>8) || conv_feature || conv_w.
// ---------------------------------------------------------------------------
__global__ __launch_bounds__(256) void part_kernel(
    const int* __restrict__ src, const int* __restrict__ dst,
    int* __restrict__ gcntC, int* __restrict__ csrA,
    const float* __restrict__ feature, unsigned short* __restrict__ fbf, long n8,
    const float* __restrict__ W, unsigned short* __restrict__ Wt,
    int E, int NC, int chunk, int nConvF)
{
    __shared__ int h[NCMAX];
    const int b = blockIdx.x, t = threadIdx.x;

    if (b < NB_P) {
        for (int i = t; i < NC; i += 256) h[i] = 0;
        __syncthreads();
        const int beg = b * chunk;
        const int end = min(beg + chunk, E);
        for (int i = beg + t; i < end; i += 256)
            atomicAdd(&h[dst[i] >> CSHIFT], 1);
        __syncthreads();
        for (int i = t; i < NC; i += 256) {
            int c = h[i];
            h[i] = c ? atomicAdd(&gcntC[i], c) : 0;
        }
        __syncthreads();
        for (int i = beg + t; i < end; i += 256) {
            int d = dst[i];
            int c = d >> CSHIFT;
            int r = atomicAdd(&h[c], 1);
            if (r < CAPC)
                csrA[(size_t)c * CAPC + r] = (src[i] << CSHIFT) | (d & (CBIN - 1));
        }
        return;
    }
    if (b < NB_P + nConvF) {
        long i = (long)(b - NB_P) * 256 + t;
        if (i < n8) {
            const float4* p = reinterpret_cast<const float4*>(feature + i * 8);
            float4 v0 = p[0], v1 = p[1];
            uint4 r;
            r.x = (unsigned int)f2bf(v0.x) | ((unsigned int)f2bf(v0.y) << 16);
            r.y = (unsigned int)f2bf(v0.z) | ((unsigned int)f2bf(v0.w) << 16);
            r.z = (unsigned int)f2bf(v1.x) | ((unsigned int)f2bf(v1.y) << 16);
            r.w = (unsigned int)f2bf(v1.z) | ((unsigned int)f2bf(v1.w) << 16);
            *reinterpret_cast<uint4*>(fbf + i * 8) = r;
        }
        return;
    }
    int i = (b - NB_P - nConvF) * 256 + t;
    if (i < D * D / 4) {
        int n  = i >> 6;
        int k0 = (i & 63) * 4;
        float a  = W[(size_t)(k0 + 0) * D + n];
        float bb = W[(size_t)(k0 + 1) * D + n];
        float c  = W[(size_t)(k0 + 2) * D + n];
        float d  = W[(size_t)(k0 + 3) * D + n];
        uint2 r;
        r.x = (unsigned int)f2bf(a) | ((unsigned int)f2bf(bb) << 16);
        r.y = (unsigned int)f2bf(c) | ((unsigned int)f2bf(d) << 16);
        *reinterpret_cast<uint2*>(Wt + (size_t)n * D + k0) = r;
    }
}

// ---------------------------------------------------------------------------
// Pass B: per-bin full node sort (256-key LDS counting sort), 1024 threads
// per block (grid is only NC=391 blocks -> widen the block to shorten the
// per-block serial passes: 32 -> 8 strided iterations per scan).
// Outputs csrB (plain src indices, node-ordered within each bin) +
// nodeBeg/nodeCnt (absolute offsets into csrB).
// ---------------------------------------------------------------------------
__global__ __launch_bounds__(1024) void regroup_kernel(
    const int* __restrict__ csrA, const int* __restrict__ gcntC,
    int* __restrict__ csrB, int* __restrict__ nodeBeg, int* __restrict__ nodeCnt,
    int N)
{
    __shared__ int h[CBIN], psum[CBIN], cur[CBIN];
    __shared__ int sorted[CAPC];               // 36.9 KB
    const int c = blockIdx.x, t = threadIdx.x;
    const int rbeg = c * CAPC;
    const int cnt = min(gcntC[c], CAPC);

    if (t < CBIN) h[t] = 0;
    __syncthreads();
    for (int i = t; i < cnt; i += 1024)
        atomicAdd(&h[csrA[(size_t)rbeg + i] & (CBIN - 1)], 1);
    __syncthreads();
    int myCnt = 0;
    if (t < CBIN) {
        myCnt = h[t];
        psum[t] = myCnt;
    }
    __syncthreads();
    for (int off = 1; off < 256; off <<= 1) {
        int v = (t >= off && t < CBIN) ? psum[t - off] : 0;
        __syncthreads();
        if (t >= off && t < CBIN) psum[t] += v;
        __syncthreads();
    }
    if (t < CBIN) {
        const int excl = psum[t] - myCnt;
        cur[t] = excl;
        int node = (c << CSHIFT) + t;
        if (node < N) {
            nodeBeg[node] = rbeg + excl;
            nodeCnt[node] = myCnt;
        }
    }
    __syncthreads();
    for (int i = t; i < cnt; i += 1024) {
        int p = csrA[(size_t)rbeg + i];
        int r = atomicAdd(&cur[p & (CBIN - 1)], 1);
        sorted[r] = p >> CSHIFT;
    }
    __syncthreads();
    for (int i = t; i < cnt; i += 1024)
        csrB[(size_t)rbeg + i] = sorted[i];
}

// ---------------------------------------------------------------------------
// Fused aggregate + GEMM at 16-node granularity.
// P0': coalesced burst copy of the group's contiguous node-sorted csrB
//      segment into LDS.
// P1: gather with the edge list in a SINGLE address space per path (no
//     mixed-address-space pointer -> no flat-load pessimization).
// P2: GEMM 16x256 @ 256x256 MFMA + bias + ReLU -> out (fp32).
// ---------------------------------------------------------------------------
#define GATHER_NODE(ELIST)                                                        \
    {                                                                             \
        int j = 0;                                                                \
        for (; j + 3 < c0; j += 4) {                                              \
            int s0 = (ELIST)[b0 + j + half];                                      \
            int s1 = (ELIST)[b0 + j + 2 + half];                                  \
            uint4 v0 = *reinterpret_cast<const uint4*>(fbf + ((size_t)s0 << 8) + colOff); \
            uint4 v1 = *reinterpret_cast<const uint4*>(fbf + ((size_t)s1 << 8) + colOff); \
            a0 += bf_lo(v0.x); a1 += bf_hi(v0.x); a2 += bf_lo(v0.y); a3 += bf_hi(v0.y); \
            a4 += bf_lo(v0.z); a5 += bf_hi(v0.z); a6 += bf_lo(v0.w); a7 += bf_hi(v0.w); \
            a0 += bf_lo(v1.x); a1 += bf_hi(v1.x); a2 += bf_lo(v1.y); a3 += bf_hi(v1.y); \
            a4 += bf_lo(v1.z); a5 += bf_hi(v1.z); a6 += bf_lo(v1.w); a7 += bf_hi(v1.w); \
        }                                                                         \
        if (j + 1 < c0) {                                                         \
            int s0 = (ELIST)[b0 + j + half];                                      \
            uint4 v0 = *reinterpret_cast<const uint4*>(fbf + ((size_t)s0 << 8) + colOff); \
            a0 += bf_lo(v0.x); a1 += bf_hi(v0.x); a2 += bf_lo(v0.y); a3 += bf_hi(v0.y); \
            a4 += bf_lo(v0.z); a5 += bf_hi(v0.z); a6 += bf_lo(v0.w); a7 += bf_hi(v0.w); \
            j += 2;                                                               \
        }                                                                         \
        if (j < c0 && half == 0) {                                                \
            int s0 = (ELIST)[b0 + j];                                             \
            uint4 v0 = *reinterpret_cast<const uint4*>(fbf + ((size_t)s0 << 8) + colOff); \
            a0 += bf_lo(v0.x); a1 += bf_hi(v0.x); a2 += bf_lo(v0.y); a3 += bf_hi(v0.y); \
            a4 += bf_lo(v0.z); a5 += bf_hi(v0.z); a6 += bf_lo(v0.w); a7 += bf_hi(v0.w); \
        }                                                                         \
    }

__global__ __launch_bounds__(256) void agg_gemm_kernel(
    const unsigned short* __restrict__ fbf,
    const int* __restrict__ csrB,
    const int* __restrict__ nodeBeg,
    const int* __restrict__ nodeCnt,
    const unsigned short* __restrict__ Wt,
    const float* __restrict__ bias,
    float* __restrict__ out, int N)
{
    __shared__ int lsrc[CAPL];
    __shared__ int lBeg[TN], lCnt[TN];
    __shared__ int sB, sL, sFit;
    __shared__ unsigned short A[TN][D + 8];    // 8448 B

    const int blk  = blockIdx.x;
    const int t    = threadIdx.x;
    const int wave = t >> 6;
    const int lane = t & 63;
    const int sub  = lane & 31;
    const int half = lane >> 5;
    const int node0 = blk * TN;
    const size_t colOff = (size_t)(sub << 3);

    if (t < TN) {
        int node = node0 + t;
        bool valid = node < N;
        lBeg[t] = valid ? nodeBeg[node] : 0;
        lCnt[t] = valid ? nodeCnt[node] : 0;
    }
    __syncthreads();
    if (t == 0) {
        int lastL = min(TN - 1, N - 1 - node0);
        sB = lBeg[0];
        sL = lBeg[lastL] + lCnt[lastL] - lBeg[0];
        sFit = (sL <= CAPL);
    }
    __syncthreads();
    const int segB = sB, segL = sL, fit = sFit;
    if (fit) {
        for (int i = t; i < segL; i += 256)
            lsrc[i] = csrB[(size_t)segB + i];
    }
    __syncthreads();

    // ---- P1: gather 4 nodes per wave ----
    for (int ni = 0; ni < 4; ++ni) {
        const int l = (wave << 2) + ni;
        const int node = node0 + l;
        float a0 = 0.f, a1 = 0.f, a2 = 0.f, a3 = 0.f;
        float a4 = 0.f, a5 = 0.f, a6 = 0.f, a7 = 0.f;
        if (node < N) {
            const int b0 = lBeg[l] - segB;
            const int c0 = lCnt[l];
            if (fit) {
                GATHER_NODE(lsrc)                      // LDS path: ds_read
            } else {
                const int* gsrc = csrB + segB;
                GATHER_NODE(gsrc)                      // global path
            }
        }
        a0 += __shfl_xor(a0, 32); a1 += __shfl_xor(a1, 32);
        a2 += __shfl_xor(a2, 32); a3 += __shfl_xor(a3, 32);
        a4 += __shfl_xor(a4, 32); a5 += __shfl_xor(a5, 32);
        a6 += __shfl_xor(a6, 32); a7 += __shfl_xor(a7, 32);
        if (half == 0) {
            uint4 r;
            r.x = (unsigned int)f2bf(a0) | ((unsigned int)f2bf(a1) << 16);
            r.y = (unsigned int)f2bf(a2) | ((unsigned int)f2bf(a3) << 16);
            r.z = (unsigned int)f2bf(a4) | ((unsigned int)f2bf(a5) << 16);
            r.w = (unsigned int)f2bf(a6) | ((unsigned int)f2bf(a7) << 16);
            *reinterpret_cast<uint4*>(&A[l][sub << 3]) = r;
        }
    }
    __syncthreads();

    // ---- P2: GEMM 16x256 ----
    const int lr = lane & 15;
    const int lg = lane >> 4;

    bf16x8 afr[8];
#pragma unroll
    for (int ks = 0; ks < 8; ++ks)
        afr[ks] = *reinterpret_cast<const bf16x8*>(&A[lr][ks * 32 + lg * 8]);

#pragma unroll
    for (int c = 0; c < 4; ++c) {
        const int ct = (wave << 2) + c;
        f32x4 acc = {0.f, 0.f, 0.f, 0.f};
        const unsigned short* bp = Wt + (size_t)(ct * 16 + lr) * D + lg * 8;
#pragma unroll
        for (int ks = 0; ks < 8; ++ks) {
            bf16x8 bfr = *reinterpret_cast<const bf16x8*>(bp + ks * 32);
            acc = __builtin_amdgcn_mfma_f32_16x16x32_bf16(afr[ks], bfr, acc, 0, 0, 0);
        }
        const float bv = bias[ct * 16 + lr];
#pragma unroll
        for (int jj = 0; jj < 4; ++jj) {
            int row = node0 + lg * 4 + jj;
            if (row < N) {
                float v = acc[jj] + bv;
                out[(size_t)row * D + ct * 16 + lr] = v > 0.f ? v : 0.f;
            }
        }
    }
}

// ---------------------------------------------------------------------------
// Fallback kernels (ws too small): direct atomic scatter + VALU linear.
// ---------------------------------------------------------------------------
__global__ __launch_bounds__(256) void scatter_kernel(
    const float* __restrict__ feature, const int* __restrict__ src,
    const int* __restrict__ dst, float* __restrict__ agg, int E)
{
    int edge = blockIdx.x * (blockDim.x >> 6) + (threadIdx.x >> 6);
    int lane = threadIdx.x & 63;
    if (edge >= E) return;
    int s = src[edge];
    int d = dst[edge];
    const float4 v = *reinterpret_cast<const float4*>(feature + (size_t)s * D + lane * 4);
    float* o = agg + (size_t)d * D + lane * 4;
    atomicAdd(o + 0, v.x);
    atomicAdd(o + 1, v.y);
    atomicAdd(o + 2, v.z);
    atomicAdd(o + 3, v.w);
}

#define BM 32
__global__ __launch_bounds__(256) void linear_relu_kernel(
    float* __restrict__ h, const float* __restrict__ W,
    const float* __restrict__ b, int n_nodes)
{
    __shared__ float sA[BM][D];
    const int node0 = blockIdx.x * BM;
    const int t = threadIdx.x;
    for (int m = 0; m < BM; ++m) {
        int nd = node0 + m;
        sA[m][t] = (nd < n_nodes) ? h[(size_t)nd * D + t] : 0.0f;
    }
    __syncthreads();
    float acc[BM];
#pragma unroll
    for (int m = 0; m < BM; ++m) acc[m] = 0.0f;
    for (int kk = 0; kk < D; ++kk) {
        float w = W[kk * D + t];
#pragma unroll
        for (int m = 0; m < BM; ++m) acc[m] += sA[m][kk] * w;
    }
    const float bias = b[t];
    for (int m = 0; m < BM; ++m) {
        int nd = node0 + m;
        if (nd < n_nodes) {
            float v = acc[m] + bias;
            h[(size_t)nd * D + t] = v > 0.0f ? v : 0.0f;
        }
    }
}

// ---------------------------------------------------------------------------
extern "C" void kernel_launch(void* const* d_in, const int* in_sizes, int n_in,
                              void* d_out, int out_size, void* d_ws, size_t ws_size,
                              hipStream_t stream)
{
    const float* feature = (const float*)d_in[0];
    const int*   src     = (const int*)d_in[1];
    const int*   dst     = (const int*)d_in[2];
    const float* W       = (const float*)d_in[3];
    const float* b       = (const float*)d_in[4];
    float*       out     = (float*)d_out;

    const int E = in_sizes[1];
    const int N = in_sizes[0] / D;
    const int NC = (N + CBIN - 1) >> CSHIFT;    // coarse bins
    const int chunk = (E + NB_P - 1) / NB_P;

    // ---- workspace layout -------------------------------------------------
    size_t off = 0;
    auto alloc = [&](size_t bytes, size_t align) {
        off = (off + align - 1) / align * align;
        size_t r = off; off += bytes; return r;
    };
    size_t o_gcntC = alloc((size_t)NC * 4, 16);
    size_t o_csrA  = alloc((size_t)NC * CAPC * 4, 16);
    size_t o_csrB  = alloc((size_t)NC * CAPC * 4, 16);
    size_t o_nbeg  = alloc((size_t)N * 4, 16);
    size_t o_ncnt  = alloc((size_t)N * 4, 16);
    size_t o_wt    = alloc((size_t)D * D * 2, 16);
    size_t o_fbf   = alloc((size_t)N * D * 2, 16);
    size_t need_full = off;

    char* ws = (char*)d_ws;

    // guards: bin capacity (mean + 8 sigma + 16) and bin count
    const double mc = (double)E / NC;
    const bool cap_ok =
        (mc + 8.0 * __builtin_sqrt(mc) + 16.0 <= (double)CAPC) &&
        (NC <= NCMAX);

    if (ws_size >= need_full && cap_ok) {
        int* gcntC   = (int*)(ws + o_gcntC);
        int* csrA    = (int*)(ws + o_csrA);
        int* csrB    = (int*)(ws + o_csrB);
        int* nodeBeg = (int*)(ws + o_nbeg);
        int* nodeCnt = (int*)(ws + o_ncnt);
        unsigned short* Wt  = (unsigned short*)(ws + o_wt);
        unsigned short* fbf = (unsigned short*)(ws + o_fbf);

        const long n8 = (long)N * D / 8;
        const int nConvF = (int)((n8 + 255) / 256);
        const int nConvW = (D * D / 4 + 255) / 256;

        hipMemsetAsync(gcntC, 0, (size_t)NC * 4, stream);

        part_kernel<<<NB_P + nConvF + nConvW, 256, 0, stream>>>(
            src, dst, gcntC, csrA, feature, fbf, n8, W, Wt,
            E, NC, chunk, nConvF);

        regroup_kernel<<<NC, 1024, 0, stream>>>(
            csrA, gcntC, csrB, nodeBeg, nodeCnt, N);

        agg_gemm_kernel<<<(N + TN - 1) / TN, 256, 0, stream>>>(
            fbf, csrB, nodeBeg, nodeCnt, Wt, b, out, N);
    } else {
        hipMemsetAsync(d_out, 0, (size_t)out_size * sizeof(float), stream);
        scatter_kernel<<<(E + 3) / 4, 256, 0, stream>>>(feature, src, dst, out, E);
        linear_relu_kernel<<<(N + BM - 1) / BM, 256, 0, stream>>>(out, W, b, N);
    }
}